// Round 4
// baseline (89.519 us; speedup 1.0000x reference)
//
#include <hip/hip_runtime.h>

// SphericalEmbedding round 4 (= round 3 with compile fix): bf16 MFMA GEMM with
// swapped operands so the C-fragment is channel-major -> f32x4 nontemporal stores.
//   pre-kernel:  W [81,2048] f32 -> WT [2048][96] bf16 (zero-padded K) in d_ws
//   main kernel: 128 pts x 128 ch per block; harmonics -> bf16 LDS tile (B);
//                WT rows -> A fragments; D[ch, pt]: lane's 4 acc regs are 4
//                consecutive channels -> global_store_dwordx4 (nontemporal).

typedef __attribute__((ext_vector_type(8))) short bf16x8;
typedef __attribute__((ext_vector_type(4))) float f32x4;

#define BM 128           // points per block
#define BN 128           // channels per block
#define LDA 104          // LDS row stride (bf16): 208 B = 52 dwords -> 2-way aliasing (free)
#define KPAD 96

// ---- compile-time normalization table ----------------------------------
constexpr double PI_D = 3.14159265358979323846;
constexpr double csqrt_c(double v) {
  if (v <= 0.0) return 0.0;
  double g = v < 1.0 ? 1.0 : v;
  for (int i = 0; i < 100; ++i) g = 0.5 * (g + v / g);
  return g;
}
struct Norms { float c[81]; };
constexpr Norms make_norms() {
  Norms n{};
  for (int l = 0; l <= 8; ++l)
    for (int m = -l; m <= l; ++m) {
      int am = m < 0 ? -m : m;
      double fr = 1.0;
      for (int i = l - am + 1; i <= l + am; ++i) fr *= (double)i;
      double v = csqrt_c((2.0 * l + 1.0) / (4.0 * PI_D) / fr);
      if (m < 0 && (am & 1)) v = -v;
      n.c[l * l + l + m] = (float)v;
    }
  return n;
}
constexpr Norms NORMS = make_norms();

__device__ __forceinline__ unsigned f2bf(float f) {   // RTN-even f32 -> bf16 bits
  unsigned u = __float_as_uint(f);
  return (u + 0x7fffu + ((u >> 16) & 1u)) >> 16;
}

// ---- pre-kernel: W f32 [81][nch] -> WT bf16 [nch][96] (padded) ---------
__global__ __launch_bounds__(256)
void wt_convert_kernel(const float* __restrict__ W, unsigned short* __restrict__ WT, int nch) {
  const int t = blockIdx.x * 256 + threadIdx.x;    // t in [0, nch*12)
  if (t >= nch * 12) return;
  const int kg = t / nch;                          // k-group of 8 (0..11)
  const int c  = t - kg * nch;                     // lanes -> consecutive c (coalesced)
  unsigned short v[8];
#pragma unroll
  for (int j = 0; j < 8; ++j) {
    const int k = kg * 8 + j;
    v[j] = (k < 81) ? (unsigned short)f2bf(W[(size_t)k * nch + c]) : (unsigned short)0;
  }
  unsigned* dst = reinterpret_cast<unsigned*>(WT + (size_t)c * KPAD + kg * 8);
#pragma unroll
  for (int j = 0; j < 4; ++j)
    dst[j] = (unsigned)v[2 * j] | ((unsigned)v[2 * j + 1] << 16);
}

// ---- main MFMA kernel ---------------------------------------------------
__global__ __launch_bounds__(256)
void sph_mfma_kernel(const float* __restrict__ pos,
                     const unsigned short* __restrict__ WT,
                     float* __restrict__ out, int nch)
{
  __shared__ unsigned short H[BM * LDA];           // 26.6 KB bf16 harmonics tile
  const int tid  = threadIdx.x;
  const int lane = tid & 63;
  const int wid  = tid >> 6;                       // 4 waves: 2(ch) x 2(pt)
  const int wc   = wid >> 1, wp = wid & 1;
  const int l15  = lane & 15, l4 = lane >> 4;
  const int mblk = blockIdx.y, nblk = blockIdx.x;

  // ---- phase 1: harmonics for 128 points -> bf16 rows in LDS -----------
  if (tid < BM) {
    const int gp = mblk * BM + tid;
    const float px = pos[gp * 3 + 0];
    const float py = pos[gp * 3 + 1];
    const float pz = pos[gp * 3 + 2];
    const float r   = sqrtf(px * px + py * py + pz * pz);
    const float inv = 1.0f / (r + 1e-8f);
    const float xn = px * inv, yn = py * inv, zn = pz * inv;
    const float x = fminf(1.0f, fmaxf(-1.0f, zn));     // cos(theta)
    const float s = sqrtf(fmaxf(0.0f, 1.0f - x * x));  // sin(theta)
    const float rho = sqrtf(xn * xn + yn * yn);
    const float c1  = rho > 0.0f ? xn / rho : 1.0f;    // cos(phi)

    float cm[9];
    cm[0] = 1.0f; cm[1] = c1;
#pragma unroll
    for (int m = 2; m <= 8; ++m) cm[m] = 2.0f * c1 * cm[m - 1] - cm[m - 2];

    float P[9][9];
#pragma unroll
    for (int m = 0; m <= 8; ++m) {
      if (m == 0) P[0][0] = 1.0f;
      else        P[m][m] = -(float)(2 * m - 1) * s * P[m - 1][m - 1];
      if (m + 1 <= 8) P[m + 1][m] = (float)(2 * m + 1) * x * P[m][m];
#pragma unroll
      for (int l = m + 2; l <= 8; ++l)
        P[l][m] = ((float)(2 * l - 1) * x * P[l - 1][m]
                   - (float)(l + m - 1) * P[l - 2][m]) / (float)(l - m);
    }

    float y[KPAD];
#pragma unroll
    for (int l = 0; l <= 8; ++l)
#pragma unroll
      for (int m = -l; m <= l; ++m) {
        const int am  = m < 0 ? -m : m;
        const int idx = l * l + l + m;
        y[idx] = NORMS.c[idx] * P[l][am] * cm[am];
      }
#pragma unroll
    for (int i = 81; i < KPAD; ++i) y[i] = 0.0f;

    unsigned* hrow = reinterpret_cast<unsigned*>(&H[tid * LDA]);
#pragma unroll
    for (int i = 0; i < KPAD / 2; ++i)
      hrow[i] = f2bf(y[2 * i]) | (f2bf(y[2 * i + 1]) << 16);
  }

  // ---- A fragments: W channels, direct 16B global loads (L2-resident) --
  bf16x8 wfrag[3][4];
  const unsigned short* wt_base =
      WT + (size_t)(nblk * BN + wc * 64 + l15) * KPAD + l4 * 8;
#pragma unroll
  for (int kk = 0; kk < 3; ++kk)
#pragma unroll
    for (int cmr = 0; cmr < 4; ++cmr)
      wfrag[kk][cmr] = *reinterpret_cast<const bf16x8*>(
          wt_base + (size_t)cmr * 16 * KPAD + kk * 32);

  __syncthreads();

  // ---- MFMA: D[ch, pt], 3 k-steps, 4x4 16x16 tiles per wave -------------
  f32x4 acc[4][4] = {};
#pragma unroll
  for (int kk = 0; kk < 3; ++kk) {
    bf16x8 hfrag[4];
#pragma unroll
    for (int pn = 0; pn < 4; ++pn)
      hfrag[pn] = *reinterpret_cast<const bf16x8*>(
          &H[(wp * 64 + pn * 16 + l15) * LDA + kk * 32 + l4 * 8]);
#pragma unroll
    for (int cmr = 0; cmr < 4; ++cmr)
#pragma unroll
      for (int pn = 0; pn < 4; ++pn)
        acc[cmr][pn] = __builtin_amdgcn_mfma_f32_16x16x32_bf16(
            wfrag[kk][cmr], hfrag[pn], acc[cmr][pn], 0, 0, 0);
  }

  // ---- epilogue: lane's 4 regs = 4 consecutive channels -> f32x4 store ---
  // D row (channel) = l4*4 + reg (+16*cmr), D col (point) = l15 (+16*pn)
  const size_t ch0 = (size_t)nblk * BN + wc * 64 + l4 * 4;
  const size_t pt0 = (size_t)mblk * BM + wp * 64 + l15;
#pragma unroll
  for (int pn = 0; pn < 4; ++pn) {
    float* orow = out + (pt0 + pn * 16) * nch + ch0;
#pragma unroll
    for (int cmr = 0; cmr < 4; ++cmr)
      __builtin_nontemporal_store(acc[cmr][pn],
                                  reinterpret_cast<f32x4*>(orow + cmr * 16));
  }
}

extern "C" void kernel_launch(void* const* d_in, const int* in_sizes, int n_in,
                              void* d_out, int out_size, void* d_ws, size_t ws_size,
                              hipStream_t stream) {
  const float* pos = (const float*)d_in[0];   // [npts, 3]
  const float* W   = (const float*)d_in[1];   // [81, nch]
  float*       out = (float*)d_out;           // [npts, nch]
  const int npts = in_sizes[0] / 3;           // 32768
  const int nch  = in_sizes[1] / 81;          // 2048

  unsigned short* WT = (unsigned short*)d_ws;  // 384 KB
  const int cvt_threads = nch * 12;
  wt_convert_kernel<<<(cvt_threads + 255) / 256, 256, 0, stream>>>(W, WT, nch);
  dim3 grid(nch / BN, npts / BM);              // (16, 256)
  sph_mfma_kernel<<<grid, 256, 0, stream>>>(pos, WT, out, nch);
}

// Round 5
// 61.218 us; speedup vs baseline: 1.4623x; 1.4623x over previous
//
#include <hip/hip_runtime.h>

// SphericalEmbedding round 5: round 4 minus the nontemporal flag (nt bypassed
// L2 write-merging -> 64B partial-line HBM writes -> 3 TB/s; plain stores let
// L2 assemble full lines).
//   pre-kernel:  W [81,2048] f32 -> WT [2048][96] bf16 (zero-padded K) in d_ws
//   main kernel: 128 pts x 128 ch per block; harmonics -> bf16 LDS tile (B);
//                WT rows -> A fragments; D[ch, pt]: lane's 4 acc regs are 4
//                consecutive channels -> global_store_dwordx4.

typedef __attribute__((ext_vector_type(8))) short bf16x8;
typedef __attribute__((ext_vector_type(4))) float f32x4;

#define BM 128           // points per block
#define BN 128           // channels per block
#define LDA 104          // LDS row stride (bf16): 208 B = 52 dwords -> 2-way aliasing (free)
#define KPAD 96

// ---- compile-time normalization table ----------------------------------
constexpr double PI_D = 3.14159265358979323846;
constexpr double csqrt_c(double v) {
  if (v <= 0.0) return 0.0;
  double g = v < 1.0 ? 1.0 : v;
  for (int i = 0; i < 100; ++i) g = 0.5 * (g + v / g);
  return g;
}
struct Norms { float c[81]; };
constexpr Norms make_norms() {
  Norms n{};
  for (int l = 0; l <= 8; ++l)
    for (int m = -l; m <= l; ++m) {
      int am = m < 0 ? -m : m;
      double fr = 1.0;
      for (int i = l - am + 1; i <= l + am; ++i) fr *= (double)i;
      double v = csqrt_c((2.0 * l + 1.0) / (4.0 * PI_D) / fr);
      if (m < 0 && (am & 1)) v = -v;
      n.c[l * l + l + m] = (float)v;
    }
  return n;
}
constexpr Norms NORMS = make_norms();

__device__ __forceinline__ unsigned f2bf(float f) {   // RTN-even f32 -> bf16 bits
  unsigned u = __float_as_uint(f);
  return (u + 0x7fffu + ((u >> 16) & 1u)) >> 16;
}

// ---- pre-kernel: W f32 [81][nch] -> WT bf16 [nch][96] (padded) ---------
__global__ __launch_bounds__(256)
void wt_convert_kernel(const float* __restrict__ W, unsigned short* __restrict__ WT, int nch) {
  const int t = blockIdx.x * 256 + threadIdx.x;    // t in [0, nch*12)
  if (t >= nch * 12) return;
  const int kg = t / nch;                          // k-group of 8 (0..11)
  const int c  = t - kg * nch;                     // lanes -> consecutive c (coalesced)
  unsigned short v[8];
#pragma unroll
  for (int j = 0; j < 8; ++j) {
    const int k = kg * 8 + j;
    v[j] = (k < 81) ? (unsigned short)f2bf(W[(size_t)k * nch + c]) : (unsigned short)0;
  }
  unsigned* dst = reinterpret_cast<unsigned*>(WT + (size_t)c * KPAD + kg * 8);
#pragma unroll
  for (int j = 0; j < 4; ++j)
    dst[j] = (unsigned)v[2 * j] | ((unsigned)v[2 * j + 1] << 16);
}

// ---- main MFMA kernel ---------------------------------------------------
__global__ __launch_bounds__(256)
void sph_mfma_kernel(const float* __restrict__ pos,
                     const unsigned short* __restrict__ WT,
                     float* __restrict__ out, int nch)
{
  __shared__ unsigned short H[BM * LDA];           // 26.6 KB bf16 harmonics tile
  const int tid  = threadIdx.x;
  const int lane = tid & 63;
  const int wid  = tid >> 6;                       // 4 waves: 2(ch) x 2(pt)
  const int wc   = wid >> 1, wp = wid & 1;
  const int l15  = lane & 15, l4 = lane >> 4;
  const int mblk = blockIdx.y, nblk = blockIdx.x;

  // ---- phase 1: harmonics for 128 points -> bf16 rows in LDS -----------
  if (tid < BM) {
    const int gp = mblk * BM + tid;
    const float px = pos[gp * 3 + 0];
    const float py = pos[gp * 3 + 1];
    const float pz = pos[gp * 3 + 2];
    const float r   = sqrtf(px * px + py * py + pz * pz);
    const float inv = 1.0f / (r + 1e-8f);
    const float xn = px * inv, yn = py * inv, zn = pz * inv;
    const float x = fminf(1.0f, fmaxf(-1.0f, zn));     // cos(theta)
    const float s = sqrtf(fmaxf(0.0f, 1.0f - x * x));  // sin(theta)
    const float rho = sqrtf(xn * xn + yn * yn);
    const float c1  = rho > 0.0f ? xn / rho : 1.0f;    // cos(phi)

    float cm[9];
    cm[0] = 1.0f; cm[1] = c1;
#pragma unroll
    for (int m = 2; m <= 8; ++m) cm[m] = 2.0f * c1 * cm[m - 1] - cm[m - 2];

    float P[9][9];
#pragma unroll
    for (int m = 0; m <= 8; ++m) {
      if (m == 0) P[0][0] = 1.0f;
      else        P[m][m] = -(float)(2 * m - 1) * s * P[m - 1][m - 1];
      if (m + 1 <= 8) P[m + 1][m] = (float)(2 * m + 1) * x * P[m][m];
#pragma unroll
      for (int l = m + 2; l <= 8; ++l)
        P[l][m] = ((float)(2 * l - 1) * x * P[l - 1][m]
                   - (float)(l + m - 1) * P[l - 2][m]) / (float)(l - m);
    }

    float y[KPAD];
#pragma unroll
    for (int l = 0; l <= 8; ++l)
#pragma unroll
      for (int m = -l; m <= l; ++m) {
        const int am  = m < 0 ? -m : m;
        const int idx = l * l + l + m;
        y[idx] = NORMS.c[idx] * P[l][am] * cm[am];
      }
#pragma unroll
    for (int i = 81; i < KPAD; ++i) y[i] = 0.0f;

    unsigned* hrow = reinterpret_cast<unsigned*>(&H[tid * LDA]);
#pragma unroll
    for (int i = 0; i < KPAD / 2; ++i)
      hrow[i] = f2bf(y[2 * i]) | (f2bf(y[2 * i + 1]) << 16);
  }

  // ---- A fragments: W channels, direct 16B global loads (L2-resident) --
  bf16x8 wfrag[3][4];
  const unsigned short* wt_base =
      WT + (size_t)(nblk * BN + wc * 64 + l15) * KPAD + l4 * 8;
#pragma unroll
  for (int kk = 0; kk < 3; ++kk)
#pragma unroll
    for (int cmr = 0; cmr < 4; ++cmr)
      wfrag[kk][cmr] = *reinterpret_cast<const bf16x8*>(
          wt_base + (size_t)cmr * 16 * KPAD + kk * 32);

  __syncthreads();

  // ---- MFMA: D[ch, pt], 3 k-steps, 4x4 16x16 tiles per wave -------------
  f32x4 acc[4][4] = {};
#pragma unroll
  for (int kk = 0; kk < 3; ++kk) {
    bf16x8 hfrag[4];
#pragma unroll
    for (int pn = 0; pn < 4; ++pn)
      hfrag[pn] = *reinterpret_cast<const bf16x8*>(
          &H[(wp * 64 + pn * 16 + l15) * LDA + kk * 32 + l4 * 8]);
#pragma unroll
    for (int cmr = 0; cmr < 4; ++cmr)
#pragma unroll
      for (int pn = 0; pn < 4; ++pn)
        acc[cmr][pn] = __builtin_amdgcn_mfma_f32_16x16x32_bf16(
            wfrag[kk][cmr], hfrag[pn], acc[cmr][pn], 0, 0, 0);
  }

  // ---- epilogue: lane's 4 regs = 4 consecutive channels -> f32x4 store ---
  // D row (channel) = l4*4 + reg (+16*cmr), D col (point) = l15 (+16*pn)
  const size_t ch0 = (size_t)nblk * BN + wc * 64 + l4 * 4;
  const size_t pt0 = (size_t)mblk * BM + wp * 64 + l15;
#pragma unroll
  for (int pn = 0; pn < 4; ++pn) {
    float* orow = out + (pt0 + pn * 16) * nch + ch0;
#pragma unroll
    for (int cmr = 0; cmr < 4; ++cmr)
      *reinterpret_cast<f32x4*>(orow + cmr * 16) = acc[cmr][pn];
  }
}

extern "C" void kernel_launch(void* const* d_in, const int* in_sizes, int n_in,
                              void* d_out, int out_size, void* d_ws, size_t ws_size,
                              hipStream_t stream) {
  const float* pos = (const float*)d_in[0];   // [npts, 3]
  const float* W   = (const float*)d_in[1];   // [81, nch]
  float*       out = (float*)d_out;           // [npts, nch]
  const int npts = in_sizes[0] / 3;           // 32768
  const int nch  = in_sizes[1] / 81;          // 2048

  unsigned short* WT = (unsigned short*)d_ws;  // 384 KB
  const int cvt_threads = nch * 12;
  wt_convert_kernel<<<(cvt_threads + 255) / 256, 256, 0, stream>>>(W, WT, nch);
  dim3 grid(nch / BN, npts / BM);              // (16, 256)
  sph_mfma_kernel<<<grid, 256, 0, stream>>>(pos, WT, out, nch);
}

// Round 6
// 55.454 us; speedup vs baseline: 1.6143x; 1.1039x over previous
//
#include <hip/hip_runtime.h>

// SphericalEmbedding round 6: R5 compute + LDS-staged epilogue.
// MFMA C-fragments can only give 4 contiguous floats/lane (64B row segments,
// partial L2 lines). Stage C tile in LDS, re-emit as fully linear wave stores
// (1 KB contiguous per instruction, whole 128B lines).
//   pre-kernel:  W [81,2048] f32 -> WT [2048][96] bf16 (zero-padded K) in d_ws
//   main kernel: 128 pts x 128 ch per block; harmonics -> bf16 LDS tile;
//                WT rows -> A fragments; D[ch, pt] via mfma_f32_16x16x32_bf16;
//                acc -> LDS C[128][132] -> linear global stores.

typedef __attribute__((ext_vector_type(8))) short bf16x8;
typedef __attribute__((ext_vector_type(4))) float f32x4;

#define BM 128           // points per block
#define BN 128           // channels per block
#define LDA 104          // H row stride (bf16): 208 B -> 2-way aliasing (free)
#define KPAD 96
#define LDSC 132         // C row stride (dwords): +4 pad vs 128

// ---- compile-time normalization table ----------------------------------
constexpr double PI_D = 3.14159265358979323846;
constexpr double csqrt_c(double v) {
  if (v <= 0.0) return 0.0;
  double g = v < 1.0 ? 1.0 : v;
  for (int i = 0; i < 100; ++i) g = 0.5 * (g + v / g);
  return g;
}
struct Norms { float c[81]; };
constexpr Norms make_norms() {
  Norms n{};
  for (int l = 0; l <= 8; ++l)
    for (int m = -l; m <= l; ++m) {
      int am = m < 0 ? -m : m;
      double fr = 1.0;
      for (int i = l - am + 1; i <= l + am; ++i) fr *= (double)i;
      double v = csqrt_c((2.0 * l + 1.0) / (4.0 * PI_D) / fr);
      if (m < 0 && (am & 1)) v = -v;
      n.c[l * l + l + m] = (float)v;
    }
  return n;
}
constexpr Norms NORMS = make_norms();

__device__ __forceinline__ unsigned f2bf(float f) {   // RTN-even f32 -> bf16 bits
  unsigned u = __float_as_uint(f);
  return (u + 0x7fffu + ((u >> 16) & 1u)) >> 16;
}

// ---- pre-kernel: W f32 [81][nch] -> WT bf16 [nch][96] (padded) ---------
__global__ __launch_bounds__(256)
void wt_convert_kernel(const float* __restrict__ W, unsigned short* __restrict__ WT, int nch) {
  const int t = blockIdx.x * 256 + threadIdx.x;    // t in [0, nch*12)
  if (t >= nch * 12) return;
  const int kg = t / nch;                          // k-group of 8 (0..11)
  const int c  = t - kg * nch;                     // lanes -> consecutive c (coalesced)
  unsigned short v[8];
#pragma unroll
  for (int j = 0; j < 8; ++j) {
    const int k = kg * 8 + j;
    v[j] = (k < 81) ? (unsigned short)f2bf(W[(size_t)k * nch + c]) : (unsigned short)0;
  }
  unsigned* dst = reinterpret_cast<unsigned*>(WT + (size_t)c * KPAD + kg * 8);
#pragma unroll
  for (int j = 0; j < 4; ++j)
    dst[j] = (unsigned)v[2 * j] | ((unsigned)v[2 * j + 1] << 16);
}

// ---- main MFMA kernel ---------------------------------------------------
__global__ __launch_bounds__(256)
void sph_mfma_kernel(const float* __restrict__ pos,
                     const unsigned short* __restrict__ WT,
                     float* __restrict__ out, int nch)
{
  // H (bf16 harmonics, 26.6 KB) and C (f32 out-tile, 67.6 KB) time-share LDS:
  // H is dead after the MFMA loop (barrier-protected below).
  __shared__ __align__(16) char smem[BM * LDSC * 4];       // 67584 B
  unsigned short* H = reinterpret_cast<unsigned short*>(smem);
  float*          C = reinterpret_cast<float*>(smem);

  const int tid  = threadIdx.x;
  const int lane = tid & 63;
  const int wid  = tid >> 6;                       // 4 waves: 2(ch) x 2(pt)
  const int wc   = wid >> 1, wp = wid & 1;
  const int l15  = lane & 15, l4 = lane >> 4;
  const int mblk = blockIdx.y, nblk = blockIdx.x;

  // ---- phase 1: harmonics for 128 points -> bf16 rows in LDS -----------
  if (tid < BM) {
    const int gp = mblk * BM + tid;
    const float px = pos[gp * 3 + 0];
    const float py = pos[gp * 3 + 1];
    const float pz = pos[gp * 3 + 2];
    const float r   = sqrtf(px * px + py * py + pz * pz);
    const float inv = 1.0f / (r + 1e-8f);
    const float xn = px * inv, yn = py * inv, zn = pz * inv;
    const float x = fminf(1.0f, fmaxf(-1.0f, zn));     // cos(theta)
    const float s = sqrtf(fmaxf(0.0f, 1.0f - x * x));  // sin(theta)
    const float rho = sqrtf(xn * xn + yn * yn);
    const float c1  = rho > 0.0f ? xn / rho : 1.0f;    // cos(phi)

    float cm[9];
    cm[0] = 1.0f; cm[1] = c1;
#pragma unroll
    for (int m = 2; m <= 8; ++m) cm[m] = 2.0f * c1 * cm[m - 1] - cm[m - 2];

    float P[9][9];
#pragma unroll
    for (int m = 0; m <= 8; ++m) {
      if (m == 0) P[0][0] = 1.0f;
      else        P[m][m] = -(float)(2 * m - 1) * s * P[m - 1][m - 1];
      if (m + 1 <= 8) P[m + 1][m] = (float)(2 * m + 1) * x * P[m][m];
#pragma unroll
      for (int l = m + 2; l <= 8; ++l)
        P[l][m] = ((float)(2 * l - 1) * x * P[l - 1][m]
                   - (float)(l + m - 1) * P[l - 2][m]) / (float)(l - m);
    }

    float y[KPAD];
#pragma unroll
    for (int l = 0; l <= 8; ++l)
#pragma unroll
      for (int m = -l; m <= l; ++m) {
        const int am  = m < 0 ? -m : m;
        const int idx = l * l + l + m;
        y[idx] = NORMS.c[idx] * P[l][am] * cm[am];
      }
#pragma unroll
    for (int i = 81; i < KPAD; ++i) y[i] = 0.0f;

    unsigned* hrow = reinterpret_cast<unsigned*>(&H[tid * LDA]);
#pragma unroll
    for (int i = 0; i < KPAD / 2; ++i)
      hrow[i] = f2bf(y[2 * i]) | (f2bf(y[2 * i + 1]) << 16);
  }

  // ---- A fragments: W channels, direct 16B global loads (L2-resident) --
  bf16x8 wfrag[3][4];
  const unsigned short* wt_base =
      WT + (size_t)(nblk * BN + wc * 64 + l15) * KPAD + l4 * 8;
#pragma unroll
  for (int kk = 0; kk < 3; ++kk)
#pragma unroll
    for (int cmr = 0; cmr < 4; ++cmr)
      wfrag[kk][cmr] = *reinterpret_cast<const bf16x8*>(
          wt_base + (size_t)cmr * 16 * KPAD + kk * 32);

  __syncthreads();

  // ---- MFMA: D[ch, pt], 3 k-steps, 4x4 16x16 tiles per wave -------------
  f32x4 acc[4][4] = {};
#pragma unroll
  for (int kk = 0; kk < 3; ++kk) {
    bf16x8 hfrag[4];
#pragma unroll
    for (int pn = 0; pn < 4; ++pn)
      hfrag[pn] = *reinterpret_cast<const bf16x8*>(
          &H[(wp * 64 + pn * 16 + l15) * LDA + kk * 32 + l4 * 8]);
#pragma unroll
    for (int cmr = 0; cmr < 4; ++cmr)
#pragma unroll
      for (int pn = 0; pn < 4; ++pn)
        acc[cmr][pn] = __builtin_amdgcn_mfma_f32_16x16x32_bf16(
            wfrag[kk][cmr], hfrag[pn], acc[cmr][pn], 0, 0, 0);
  }

  __syncthreads();   // H is now dead; smem becomes the C tile

  // ---- phase 5: acc -> LDS C[pt][ch] -------------------------------------
  // D row (channel) = l4*4 + reg (+16*cmr), D col (point) = l15 (+16*pn)
#pragma unroll
  for (int pn = 0; pn < 4; ++pn) {
    const int crow = wp * 64 + pn * 16 + l15;          // point (local row)
#pragma unroll
    for (int cmr = 0; cmr < 4; ++cmr)
      *reinterpret_cast<f32x4*>(&C[crow * LDSC + wc * 64 + cmr * 16 + l4 * 4]) =
          acc[cmr][pn];
  }

  __syncthreads();

  // ---- phase 7: linear re-emit, 1 KB contiguous per wave instruction -----
  const size_t obase = (size_t)(mblk * BM) * nch + (size_t)nblk * BN;
#pragma unroll
  for (int i = 0; i < 16; ++i) {
    const int f = i * 1024 + tid * 4;                  // flat tile idx (floats)
    const int r = f >> 7;                              // point row 0..127
    const int c = f & 127;                             // channel col
    const f32x4 v = *reinterpret_cast<const f32x4*>(&C[r * LDSC + c]);
    *reinterpret_cast<f32x4*>(out + obase + (size_t)r * nch + c) = v;
  }
}

extern "C" void kernel_launch(void* const* d_in, const int* in_sizes, int n_in,
                              void* d_out, int out_size, void* d_ws, size_t ws_size,
                              hipStream_t stream) {
  const float* pos = (const float*)d_in[0];   // [npts, 3]
  const float* W   = (const float*)d_in[1];   // [81, nch]
  float*       out = (float*)d_out;           // [npts, nch]
  const int npts = in_sizes[0] / 3;           // 32768
  const int nch  = in_sizes[1] / 81;          // 2048

  unsigned short* WT = (unsigned short*)d_ws;  // 384 KB
  const int cvt_threads = nch * 12;
  wt_convert_kernel<<<(cvt_threads + 255) / 256, 256, 0, stream>>>(W, WT, nch);
  dim3 grid(nch / BN, npts / BM);              // (16, 256)
  sph_mfma_kernel<<<grid, 256, 0, stream>>>(pos, WT, out, nch);
}